// Round 5
// baseline (300.488 us; speedup 1.0000x reference)
//
#include <hip/hip_runtime.h>
#include <math.h>

// ---------------------------------------------------------------------------
// GOTSim: GCN feats (bf16 hi/lo-split MFMA GEMM, W planes precomputed)
// -> fused agg+sim (reduced 32x32 GED cost) -> batched JV LAP with full
// lapjv init (column reduction + reduction transfer + capped ARR) -> head.
// B=256 pairs, S=32 nodes, L=3 layers, FIN=512, F=256.
// ---------------------------------------------------------------------------

#define LAP_INF 1e30f

typedef __attribute__((ext_vector_type(8))) short short8;
typedef __attribute__((ext_vector_type(4))) float f32x4;

// ---- build adjacency counts (multi-edges counted, like segment_sum) -------
__global__ __launch_bounds__(256) void count_edges_k(const int* __restrict__ eiq,
                                                     const int* __restrict__ eic,
                                                     float* __restrict__ adj, int ne) {
  int e = blockIdx.x * 256 + threadIdx.x;
  if (e >= ne) return;
  const int side = blockIdx.y;
  const int* ei = side ? eic : eiq;
  int s = ei[e];
  int d = ei[ne + e];
  int g = d >> 5;
  atomicAdd(&adj[((side << 8) + g) * 1024 + (d & 31) * 32 + (s & 31)], 1.0f);
}

// ---- add self loops, deg^-1/2 sym-normalize (in place) --------------------
__global__ __launch_bounds__(256) void norm_adj_k(float* __restrict__ adj) {
  __shared__ float s[1024];
  __shared__ float dinv[32];
  float* A = adj + (size_t)blockIdx.x * 1024;
  const int t = threadIdx.x;
  for (int k = t; k < 1024; k += 256) s[k] = A[k];
  __syncthreads();
  if (t < 32) s[t * 32 + t] += 1.0f;
  __syncthreads();
  if (t < 32) {
    float d = 0.f;
#pragma unroll
    for (int j = 0; j < 32; ++j) d += s[t * 32 + j];
    dinv[t] = rsqrtf(d);
  }
  __syncthreads();
  for (int k = t; k < 1024; k += 256)
    A[k] = s[k] * dinv[k >> 5] * dinv[k & 31];
}

// ---- bf16 hi/lo split helpers ---------------------------------------------
__device__ __forceinline__ unsigned short bf16_rne(float x) {
  unsigned u = __float_as_uint(x);
  return (unsigned short)((u + 0x7fffu + ((u >> 16) & 1u)) >> 16);
}
__device__ __forceinline__ void split2(float x, unsigned short& h, unsigned short& l) {
  h = bf16_rne(x);
  l = (unsigned short)(__float_as_uint(x - __uint_as_float((unsigned)h << 16)) >> 16);
}

// ---- W [K][256] -> transposed hi/lo bf16 planes [256][K], all 3 layers ----
__global__ __launch_bounds__(256) void wsplit_k(const float* __restrict__ W0,
                                                const float* __restrict__ W1,
                                                const float* __restrict__ W2,
                                                unsigned short* __restrict__ WP) {
  const int z = blockIdx.z;
  if (z > 0 && blockIdx.x >= 8) return;
  const float* W = (z == 0) ? W0 : (z == 1) ? W1 : W2;
  const int K = (z == 0) ? 512 : 256;
  unsigned short* WH = WP + ((z == 0) ? 0 : (z == 1) ? 262144 : 393216);
  unsigned short* WL = WH + ((z == 0) ? 131072 : 65536);
  __shared__ float tile[32][33];
  const int k0 = blockIdx.x * 32, n0 = blockIdx.y * 32;
  const int tr = threadIdx.x & 31, tc = threadIdx.x >> 5;
  for (int rr = tc; rr < 32; rr += 8)
    tile[rr][tr] = W[(size_t)(k0 + rr) * 256 + n0 + tr];
  __syncthreads();
  for (int rr = tc; rr < 32; rr += 8) {
    float v = tile[tr][rr];
    unsigned short h, l;
    split2(v, h, l);
    WH[(size_t)(n0 + rr) * K + k0 + tr] = h;
    WL[(size_t)(n0 + rr) * K + k0 + tr] = l;
  }
}

// ---- Y = A @ W via hi/lo bf16-split MFMA ----------------------------------
// 64x128 tile, 4 waves, K-step 32; A fp32 [M][K]; W as bf16 planes [256][K].
// LDS row stride 40 shorts: 16B-aligned b128 frags, 2-way banks only (free).
template <int K>
__global__ __launch_bounds__(256) void gemm_k(const float* __restrict__ Aq,
                                              const float* __restrict__ Ac,
                                              const unsigned short* __restrict__ WH,
                                              const unsigned short* __restrict__ WL,
                                              float* __restrict__ Y) {
  const float* A = blockIdx.z ? Ac : Aq;
  float* Yp = Y + (size_t)blockIdx.z * 2097152;
  const int m0 = blockIdx.x * 64;
  const int n0 = blockIdx.y * 128;
  __shared__ __align__(16) unsigned short As[2][64 * 40];
  __shared__ __align__(16) unsigned short Bs[2][128 * 40];
  const int t = threadIdx.x;
  const int wave = t >> 6, lane = t & 63;
  const int lrow = lane & 15, kgrp = lane >> 4;

  f32x4 acc[8];
#pragma unroll
  for (int j = 0; j < 8; ++j) acc[j] = (f32x4){0.f, 0.f, 0.f, 0.f};

  for (int kt = 0; kt < K; kt += 32) {
    // A: fp32 -> hi/lo bf16 (2 float4 per thread)
#pragma unroll
    for (int p = 0; p < 2; ++p) {
      const int u = t + p * 256;
      const int row = u >> 3, seg = u & 7;
      float4 xv = *(const float4*)(A + (size_t)(m0 + row) * K + kt + seg * 4);
      ushort4 h, l;
      split2(xv.x, h.x, l.x); split2(xv.y, h.y, l.y);
      split2(xv.z, h.z, l.z); split2(xv.w, h.w, l.w);
      *(ushort4*)&As[0][row * 40 + seg * 4] = h;
      *(ushort4*)&As[1][row * 40 + seg * 4] = l;
    }
    // B: precomputed planes, pure b128 copies (2 chunks per plane per thread)
#pragma unroll
    for (int p = 0; p < 2; ++p) {
      const int u = t + p * 256;
      const int row = u >> 2, seg = u & 3;
      *(short8*)&Bs[0][row * 40 + seg * 8] =
          *(const short8*)&WH[(size_t)(n0 + row) * K + kt + seg * 8];
      *(short8*)&Bs[1][row * 40 + seg * 8] =
          *(const short8*)&WL[(size_t)(n0 + row) * K + kt + seg * 8];
    }
    __syncthreads();
    const int aoff = (wave * 16 + lrow) * 40 + kgrp * 8;
    short8 ah = *(const short8*)&As[0][aoff];
    short8 al = *(const short8*)&As[1][aoff];
#pragma unroll
    for (int nf = 0; nf < 8; ++nf) {
      const int boff = (nf * 16 + lrow) * 40 + kgrp * 8;
      short8 bh = *(const short8*)&Bs[0][boff];
      short8 bl = *(const short8*)&Bs[1][boff];
      acc[nf] = __builtin_amdgcn_mfma_f32_16x16x32_bf16(ah, bh, acc[nf], 0, 0, 0);
      acc[nf] = __builtin_amdgcn_mfma_f32_16x16x32_bf16(ah, bl, acc[nf], 0, 0, 0);
      acc[nf] = __builtin_amdgcn_mfma_f32_16x16x32_bf16(al, bh, acc[nf], 0, 0, 0);
    }
    __syncthreads();
  }
#pragma unroll
  for (int nf = 0; nf < 8; ++nf)
#pragma unroll
    for (int r = 0; r < 4; ++r)
      Yp[(size_t)(m0 + wave * 16 + kgrp * 4 + r) * 256 + n0 + nf * 16 + lrow] =
          acc[nf][r];
}

// ---- fused agg (P = Ahat@Y + b) + sim (reduced 32x32 GED cost) ------------
// Also writes relu(P) as the next layer's GEMM A operand.
__global__ __launch_bounds__(256) void aggsim_k(const float* __restrict__ Y,
                                                const float* __restrict__ adj,
                                                const float* __restrict__ bias,
                                                const float* __restrict__ delp,
                                                const float* __restrict__ insp,
                                                float* __restrict__ sim, int l,
                                                float* __restrict__ PAq,
                                                float* __restrict__ PAc,
                                                int writePA) {
  __shared__ float qs[32][256];
  __shared__ float cs[32][256];
  __shared__ float Aq[1024];
  __shared__ float Ac[1024];
  __shared__ float dq[32];
  __shared__ float dic[32];
  const int b = blockIdx.x, t = threadIdx.x;
  const float* Yq = Y + (size_t)b * 8192;
  const float* Yc = Y + 2097152 + (size_t)b * 8192;
  for (int k = t; k < 1024; k += 256) {
    Aq[k] = adj[(size_t)b * 1024 + k];
    Ac[k] = adj[(size_t)(256 + b) * 1024 + k];
  }
  __syncthreads();
  const float bf = bias[t];
  {
    float y[32];
#pragma unroll
    for (int j = 0; j < 32; ++j) y[j] = Yq[(size_t)j * 256 + t];
#pragma unroll 4
    for (int i = 0; i < 32; ++i) {
      float acc = bf;
#pragma unroll
      for (int j = 0; j < 32; ++j) acc = fmaf(Aq[i * 32 + j], y[j], acc);
      qs[i][t] = acc;
      if (writePA) PAq[(size_t)(b * 32 + i) * 256 + t] = fmaxf(acc, 0.f);
    }
  }
  {
    float y[32];
#pragma unroll
    for (int j = 0; j < 32; ++j) y[j] = Yc[(size_t)j * 256 + t];
#pragma unroll 4
    for (int i = 0; i < 32; ++i) {
      float acc = bf;
#pragma unroll
      for (int j = 0; j < 32; ++j) acc = fmaf(Ac[i * 32 + j], y[j], acc);
      cs[i][t] = acc;
      if (writePA) PAc[(size_t)(b * 32 + i) * 256 + t] = fmaxf(acc, 0.f);
    }
  }
  __syncthreads();
  if (t < 64) {
    const int i = t & 31;
    const float* pvec = (t < 32) ? delp : insp;
    float a = 0.f;
#pragma unroll 8
    for (int f = 0; f < 256; ++f) {
      int idx = (f + i) & 255;
      float xv = (t < 32) ? qs[i][idx] : cs[i][idx];
      a = fmaf(xv, pvec[idx], a);
    }
    if (t < 32) dq[i] = -a;
    else        dic[i] = -a;
  }
  __syncthreads();
  float* dst = sim + ((size_t)b * 3 + l) * 1024;
  const int ci = t & 31;
  const int qb = (t >> 5) << 2;
  float acc[4] = {0.f, 0.f, 0.f, 0.f};
#pragma unroll 8
  for (int f = 0; f < 256; ++f) {
    int idx = (f + ci) & 255;
    float cv = cs[ci][idx];
#pragma unroll
    for (int k = 0; k < 4; ++k) acc[k] = fmaf(qs[qb + k][idx], cv, acc[k]);
  }
  const float dj = dic[ci];
#pragma unroll
  for (int k = 0; k < 4; ++k) {
    float alt = dq[qb + k] + dj;
    dst[(qb + k) * 32 + ci] = fminf(-acc[k], alt);
  }
}

// ---- wave primitives for the LAP ------------------------------------------
template <int CTRL>
__device__ __forceinline__ float dpp_ror_min(float x) {
  int y = __builtin_amdgcn_update_dpp(0, __float_as_int(x), CTRL, 0xf, 0xf, true);
  return fminf(x, __int_as_float(y));
}
template <int CTRL>
__device__ __forceinline__ float dpp_ror_add(float x) {
  int y = __builtin_amdgcn_update_dpp(0, __float_as_int(x), CTRL, 0xf, 0xf, true);
  return x + __int_as_float(y);
}
__device__ __forceinline__ float rdlane_f(float x, int l) {
  return __int_as_float(__builtin_amdgcn_readlane(__float_as_int(x), l));
}
__device__ __forceinline__ float wave_min32(float x) {
  x = dpp_ror_min<0x121>(x);
  x = dpp_ror_min<0x122>(x);
  x = dpp_ror_min<0x124>(x);
  x = dpp_ror_min<0x128>(x);
  return fminf(rdlane_f(x, 0), rdlane_f(x, 16));
}

// ---- 32x32 Jonker-Volgenant: CR + reduction transfer + capped ARR + SAP ---
__global__ __launch_bounds__(64) void lap_k(const float* __restrict__ sim,
                                            float* __restrict__ mcost) {
  __shared__ float Cl[1024];
  const int lane = threadIdx.x;
  const float* src = sim + (size_t)blockIdx.x * 1024;
  for (int k = lane; k < 1024; k += 64) Cl[k] = src[k];
  if (lane >= 32) return;  // same-wave LDS ordering covers staging

  // column reduction; lane's column kept in registers (static-index use only)
  float c[32];
  float minv = LAP_INF;
  int imin = 0;
#pragma unroll
  for (int i = 0; i < 32; ++i) {
    c[i] = src[i * 32 + lane];
    if (c[i] < minv) { minv = c[i]; imin = i; }
  }
  float vj = minv;     // lane as column: dual v
  float u = 0.0f;      // lane as row: dual u
  int col4row = -1;    // lane as row
  int row4col = -1;    // lane as col
#pragma unroll
  for (int r = 0; r < 32; ++r) {
    unsigned long long bal = __ballot(imin == r);
    if (bal) {
      int j = 63 - __clzll(bal);
      if (lane == j) row4col = r;
      if (lane == r) col4row = j;
    }
  }

  // reduction transfer: v[j_r] -= second-best slack; u[r] += same (stays tight)
#pragma unroll
  for (int r = 0; r < 32; ++r) {
    int jr = __builtin_amdgcn_readlane(col4row, r);
    if (jr >= 0) {
      float red = c[r] - vj;  // u[r]==0 for CR-matched rows here
      float m = wave_min32((lane == jr) ? LAP_INF : red);
      if (lane == jr) vj -= m;
      if (lane == r) u += m;
    }
  }

  // augmenting row reduction (capped; leftovers go to SAP)
  unsigned long long fm = __ballot(col4row < 0);
  int guard = 0;
  while (fm && guard++ < 96) {
    const int r = __ffsll(fm) - 1;
    fm &= fm - 1;
    float red = Cl[r * 32 + lane] - vj;  // u[r]==0 for free rows
    float m1 = wave_min32(red);
    unsigned long long b1 = __ballot(red == m1);
    int j1 = __ffsll(b1) - 1;
    float m2 = wave_min32((lane == j1) ? LAP_INF : red);
    int prev = __builtin_amdgcn_readlane(row4col, j1);
    if (m1 < m2) {
      if (lane == j1) { vj -= (m2 - m1); row4col = r; }
      if (lane == r) { col4row = j1; u = m2; }
      if (prev >= 0) {
        if (lane == prev) { col4row = -1; u = 0.0f; }  // slacks >= 0 with u=0
        fm |= 1ull << prev;
      }
    } else if (prev < 0) {
      if (lane == j1) row4col = r;
      if (lane == r) { col4row = j1; u = m2; }  // m2==m1: tight
    }
    // tie with occupied column: leave row free for SAP
  }

  // shortest augmenting path for remaining free rows
  unsigned long long freemask = __ballot(col4row < 0);
  while (freemask) {
    const int cur = __ffsll(freemask) - 1;
    freemask &= freemask - 1;
    float shortest = LAP_INF;
    int path = -1;
    bool SC = false;
    int i = cur;
    float minval = 0.0f;
    int sink;
    while (true) {
      float ui = rdlane_f(u, i);
      float r = minval + Cl[i * 32 + lane] - ui - vj;
      bool better = (!SC) && (r < shortest);
      shortest = better ? r : shortest;
      path = better ? i : path;
      float masked = SC ? LAP_INF : shortest;
      float mv = wave_min32(masked);
      unsigned long long bal = __ballot(masked == mv);  // exact: min keeps bits
      int j = __ffsll(bal) - 1;                         // lowest-index tie-break
      minval = mv;
      SC = SC || (lane == j);
      int rj = __builtin_amdgcn_readlane(row4col, j);
      if (rj < 0) { sink = j; break; }
      i = rj;
    }
    unsigned long long scmask = __ballot(SC);
    if (SC) vj -= minval - shortest;
    int sidx = (col4row < 0) ? lane : col4row;
    float sh_j0 = __shfl(shortest, sidx);
    bool scanned = (col4row >= 0) && ((scmask >> col4row) & 1ull) && (col4row != sink);
    if (lane == cur) u += minval;
    else if (scanned) u += minval - sh_j0;
    int j = sink;
    while (true) {
      int i2 = __builtin_amdgcn_readlane(path, j);
      int jn = __builtin_amdgcn_readlane(col4row, i2);
      if (lane == j) row4col = i2;
      if (lane == i2) col4row = j;
      j = jn;
      if (i2 == cur) break;
    }
  }
  // total assignment cost
  float cc = Cl[lane * 32 + col4row];
  cc = dpp_ror_add<0x121>(cc);
  cc = dpp_ror_add<0x122>(cc);
  cc = dpp_ror_add<0x124>(cc);
  cc = dpp_ror_add<0x128>(cc);
  float tot = rdlane_f(cc, 0) + rdlane_f(cc, 16);
  if (lane == 0) mcost[blockIdx.x] = tot;
}

// ---- head: sigmoid(sum_l mcost/S * w_l + b) -------------------------------
__global__ void final_k(const float* __restrict__ mcost,
                        const float* __restrict__ ot_w,
                        const float* __restrict__ ot_b,
                        float* __restrict__ out) {
  int b = threadIdx.x;
  if (b < 256) {
    float s = ot_b[0];
#pragma unroll
    for (int l = 0; l < 3; ++l)
      s += mcost[b * 3 + l] * (1.0f / 32.0f) * ot_w[l];
    out[b] = 1.0f / (1.0f + expf(-s));
  }
}

extern "C" void kernel_launch(void* const* d_in, const int* in_sizes, int n_in,
                              void* d_out, int out_size, void* d_ws, size_t ws_size,
                              hipStream_t stream) {
  const float* x_q  = (const float*)d_in[0];
  const float* x_c  = (const float*)d_in[1];
  const float* W0   = (const float*)d_in[2];
  const float* b0   = (const float*)d_in[3];
  const float* W1   = (const float*)d_in[4];
  const float* b1   = (const float*)d_in[5];
  const float* W2   = (const float*)d_in[6];
  const float* b2   = (const float*)d_in[7];
  const float* delp = (const float*)d_in[8];
  const float* insp = (const float*)d_in[9];
  const float* ot_w = (const float*)d_in[10];
  const float* ot_b = (const float*)d_in[11];
  const int* ei_q   = (const int*)d_in[12];
  const int* ei_c   = (const int*)d_in[13];
  float* out = (float*)d_out;

  float* ws    = (float*)d_ws;
  float* adj   = ws;                 // 512*1024              = 524288
  float* Y     = adj + 524288;       // 2*8192*256            = 4194304
  float* PAq   = Y + 4194304;        // 8192*256              = 2097152
  float* PAc   = PAq + 2097152;      // 8192*256              = 2097152
  float* sim   = PAc + 2097152;      // 768*1024              = 786432
  float* mcost = sim + 786432;       // 768
  unsigned short* WP = (unsigned short*)(mcost + 768);  // 524288 ushorts
  unsigned short* WH0 = WP;                 // 256*512
  unsigned short* WL0 = WP + 131072;
  unsigned short* WH1 = WP + 262144;        // 256*256
  unsigned short* WL1 = WP + 327680;
  unsigned short* WH2 = WP + 393216;
  unsigned short* WL2 = WP + 458752;

  const int ne = in_sizes[12] / 2;

  (void)hipMemsetAsync(adj, 0, 512 * 1024 * sizeof(float), stream);
  count_edges_k<<<dim3((ne + 255) / 256, 2), 256, 0, stream>>>(ei_q, ei_c, adj, ne);
  norm_adj_k<<<512, 256, 0, stream>>>(adj);
  wsplit_k<<<dim3(16, 8, 3), 256, 0, stream>>>(W0, W1, W2, WP);

  gemm_k<512><<<dim3(128, 2, 2), 256, 0, stream>>>(x_q, x_c, WH0, WL0, Y);
  aggsim_k<<<256, 256, 0, stream>>>(Y, adj, b0, delp, insp, sim, 0, PAq, PAc, 1);
  gemm_k<256><<<dim3(128, 2, 2), 256, 0, stream>>>(PAq, PAc, WH1, WL1, Y);
  aggsim_k<<<256, 256, 0, stream>>>(Y, adj, b1, delp + 256, insp + 256, sim, 1, PAq, PAc, 1);
  gemm_k<256><<<dim3(128, 2, 2), 256, 0, stream>>>(PAq, PAc, WH2, WL2, Y);
  aggsim_k<<<256, 256, 0, stream>>>(Y, adj, b2, delp + 512, insp + 512, sim, 2, PAq, PAc, 0);

  lap_k<<<768, 64, 0, stream>>>(sim, mcost);
  final_k<<<1, 256, 0, stream>>>(mcost, ot_w, ot_b, out);
}

// Round 6
// 278.132 us; speedup vs baseline: 1.0804x; 1.0804x over previous
//
#include <hip/hip_runtime.h>
#include <math.h>

// ---------------------------------------------------------------------------
// GOTSim: GCN feats (bf16 hi/lo-split MFMA GEMM, W planes precomputed)
// -> fused agg+sim (reduced 32x32 GED cost) -> batched JV LAP (column
// reduction + parallel row reduction + zero-arc greedy + SAP) -> head.
// B=256 pairs, S=32 nodes, L=3 layers, FIN=512, F=256.
// ---------------------------------------------------------------------------

#define LAP_INF 1e30f

typedef __attribute__((ext_vector_type(8))) short short8;
typedef __attribute__((ext_vector_type(4))) float f32x4;

// ---- build adjacency counts (multi-edges counted, like segment_sum) -------
__global__ __launch_bounds__(256) void count_edges_k(const int* __restrict__ eiq,
                                                     const int* __restrict__ eic,
                                                     float* __restrict__ adj, int ne) {
  int e = blockIdx.x * 256 + threadIdx.x;
  if (e >= ne) return;
  const int side = blockIdx.y;
  const int* ei = side ? eic : eiq;
  int s = ei[e];
  int d = ei[ne + e];
  int g = d >> 5;
  atomicAdd(&adj[((side << 8) + g) * 1024 + (d & 31) * 32 + (s & 31)], 1.0f);
}

// ---- add self loops, deg^-1/2 sym-normalize (in place) --------------------
__global__ __launch_bounds__(256) void norm_adj_k(float* __restrict__ adj) {
  __shared__ float s[1024];
  __shared__ float dinv[32];
  float* A = adj + (size_t)blockIdx.x * 1024;
  const int t = threadIdx.x;
  for (int k = t; k < 1024; k += 256) s[k] = A[k];
  __syncthreads();
  if (t < 32) s[t * 32 + t] += 1.0f;
  __syncthreads();
  if (t < 32) {
    float d = 0.f;
#pragma unroll
    for (int j = 0; j < 32; ++j) d += s[t * 32 + j];
    dinv[t] = rsqrtf(d);
  }
  __syncthreads();
  for (int k = t; k < 1024; k += 256)
    A[k] = s[k] * dinv[k >> 5] * dinv[k & 31];
}

// ---- bf16 hi/lo split helpers ---------------------------------------------
__device__ __forceinline__ unsigned short bf16_rne(float x) {
  unsigned u = __float_as_uint(x);
  return (unsigned short)((u + 0x7fffu + ((u >> 16) & 1u)) >> 16);
}
__device__ __forceinline__ void split2(float x, unsigned short& h, unsigned short& l) {
  h = bf16_rne(x);
  l = (unsigned short)(__float_as_uint(x - __uint_as_float((unsigned)h << 16)) >> 16);
}

// ---- W [K][256] -> transposed hi/lo bf16 planes [256][K], all 3 layers ----
__global__ __launch_bounds__(256) void wsplit_k(const float* __restrict__ W0,
                                                const float* __restrict__ W1,
                                                const float* __restrict__ W2,
                                                unsigned short* __restrict__ WP) {
  const int z = blockIdx.z;
  if (z > 0 && blockIdx.x >= 8) return;
  const float* W = (z == 0) ? W0 : (z == 1) ? W1 : W2;
  const int K = (z == 0) ? 512 : 256;
  unsigned short* WH = WP + ((z == 0) ? 0 : (z == 1) ? 262144 : 393216);
  unsigned short* WL = WH + ((z == 0) ? 131072 : 65536);
  __shared__ float tile[32][33];
  const int k0 = blockIdx.x * 32, n0 = blockIdx.y * 32;
  const int tr = threadIdx.x & 31, tc = threadIdx.x >> 5;
  for (int rr = tc; rr < 32; rr += 8)
    tile[rr][tr] = W[(size_t)(k0 + rr) * 256 + n0 + tr];
  __syncthreads();
  for (int rr = tc; rr < 32; rr += 8) {
    float v = tile[tr][rr];
    unsigned short h, l;
    split2(v, h, l);
    WH[(size_t)(n0 + rr) * K + k0 + tr] = h;
    WL[(size_t)(n0 + rr) * K + k0 + tr] = l;
  }
}

// ---- Y = A @ W via hi/lo bf16-split MFMA ----------------------------------
// 64x128 tile, 4 waves, K-step 32; A fp32 [M][K]; W as bf16 planes [256][K].
template <int K>
__global__ __launch_bounds__(256) void gemm_k(const float* __restrict__ Aq,
                                              const float* __restrict__ Ac,
                                              const unsigned short* __restrict__ WH,
                                              const unsigned short* __restrict__ WL,
                                              float* __restrict__ Y) {
  const float* A = blockIdx.z ? Ac : Aq;
  float* Yp = Y + (size_t)blockIdx.z * 2097152;
  const int m0 = blockIdx.x * 64;
  const int n0 = blockIdx.y * 128;
  __shared__ __align__(16) unsigned short As[2][64 * 40];
  __shared__ __align__(16) unsigned short Bs[2][128 * 40];
  const int t = threadIdx.x;
  const int wave = t >> 6, lane = t & 63;
  const int lrow = lane & 15, kgrp = lane >> 4;

  f32x4 acc[8];
#pragma unroll
  for (int j = 0; j < 8; ++j) acc[j] = (f32x4){0.f, 0.f, 0.f, 0.f};

  for (int kt = 0; kt < K; kt += 32) {
#pragma unroll
    for (int p = 0; p < 2; ++p) {
      const int u = t + p * 256;
      const int row = u >> 3, seg = u & 7;
      float4 xv = *(const float4*)(A + (size_t)(m0 + row) * K + kt + seg * 4);
      ushort4 h, l;
      split2(xv.x, h.x, l.x); split2(xv.y, h.y, l.y);
      split2(xv.z, h.z, l.z); split2(xv.w, h.w, l.w);
      *(ushort4*)&As[0][row * 40 + seg * 4] = h;
      *(ushort4*)&As[1][row * 40 + seg * 4] = l;
    }
#pragma unroll
    for (int p = 0; p < 2; ++p) {
      const int u = t + p * 256;
      const int row = u >> 2, seg = u & 3;
      *(short8*)&Bs[0][row * 40 + seg * 8] =
          *(const short8*)&WH[(size_t)(n0 + row) * K + kt + seg * 8];
      *(short8*)&Bs[1][row * 40 + seg * 8] =
          *(const short8*)&WL[(size_t)(n0 + row) * K + kt + seg * 8];
    }
    __syncthreads();
    const int aoff = (wave * 16 + lrow) * 40 + kgrp * 8;
    short8 ah = *(const short8*)&As[0][aoff];
    short8 al = *(const short8*)&As[1][aoff];
#pragma unroll
    for (int nf = 0; nf < 8; ++nf) {
      const int boff = (nf * 16 + lrow) * 40 + kgrp * 8;
      short8 bh = *(const short8*)&Bs[0][boff];
      short8 bl = *(const short8*)&Bs[1][boff];
      acc[nf] = __builtin_amdgcn_mfma_f32_16x16x32_bf16(ah, bh, acc[nf], 0, 0, 0);
      acc[nf] = __builtin_amdgcn_mfma_f32_16x16x32_bf16(ah, bl, acc[nf], 0, 0, 0);
      acc[nf] = __builtin_amdgcn_mfma_f32_16x16x32_bf16(al, bh, acc[nf], 0, 0, 0);
    }
    __syncthreads();
  }
#pragma unroll
  for (int nf = 0; nf < 8; ++nf)
#pragma unroll
    for (int r = 0; r < 4; ++r)
      Yp[(size_t)(m0 + wave * 16 + kgrp * 4 + r) * 256 + n0 + nf * 16 + lrow] =
          acc[nf][r];
}

// ---- fused agg (P = Ahat@Y + b) + sim (reduced 32x32 GED cost) ------------
__global__ __launch_bounds__(256) void aggsim_k(const float* __restrict__ Y,
                                                const float* __restrict__ adj,
                                                const float* __restrict__ bias,
                                                const float* __restrict__ delp,
                                                const float* __restrict__ insp,
                                                float* __restrict__ sim, int l,
                                                float* __restrict__ PAq,
                                                float* __restrict__ PAc,
                                                int writePA) {
  __shared__ float qs[32][256];
  __shared__ float cs[32][256];
  __shared__ float Aq[1024];
  __shared__ float Ac[1024];
  __shared__ float dq[32];
  __shared__ float dic[32];
  const int b = blockIdx.x, t = threadIdx.x;
  const float* Yq = Y + (size_t)b * 8192;
  const float* Yc = Y + 2097152 + (size_t)b * 8192;
  for (int k = t; k < 1024; k += 256) {
    Aq[k] = adj[(size_t)b * 1024 + k];
    Ac[k] = adj[(size_t)(256 + b) * 1024 + k];
  }
  __syncthreads();
  const float bf = bias[t];
  {
    float y[32];
#pragma unroll
    for (int j = 0; j < 32; ++j) y[j] = Yq[(size_t)j * 256 + t];
#pragma unroll 4
    for (int i = 0; i < 32; ++i) {
      float acc = bf;
#pragma unroll
      for (int j = 0; j < 32; ++j) acc = fmaf(Aq[i * 32 + j], y[j], acc);
      qs[i][t] = acc;
      if (writePA) PAq[(size_t)(b * 32 + i) * 256 + t] = fmaxf(acc, 0.f);
    }
  }
  {
    float y[32];
#pragma unroll
    for (int j = 0; j < 32; ++j) y[j] = Yc[(size_t)j * 256 + t];
#pragma unroll 4
    for (int i = 0; i < 32; ++i) {
      float acc = bf;
#pragma unroll
      for (int j = 0; j < 32; ++j) acc = fmaf(Ac[i * 32 + j], y[j], acc);
      cs[i][t] = acc;
      if (writePA) PAc[(size_t)(b * 32 + i) * 256 + t] = fmaxf(acc, 0.f);
    }
  }
  __syncthreads();
  if (t < 64) {
    const int i = t & 31;
    const float* pvec = (t < 32) ? delp : insp;
    float a = 0.f;
#pragma unroll 8
    for (int f = 0; f < 256; ++f) {
      int idx = (f + i) & 255;
      float xv = (t < 32) ? qs[i][idx] : cs[i][idx];
      a = fmaf(xv, pvec[idx], a);
    }
    if (t < 32) dq[i] = -a;
    else        dic[i] = -a;
  }
  __syncthreads();
  float* dst = sim + ((size_t)b * 3 + l) * 1024;
  const int ci = t & 31;
  const int qb = (t >> 5) << 2;
  float acc[4] = {0.f, 0.f, 0.f, 0.f};
#pragma unroll 8
  for (int f = 0; f < 256; ++f) {
    int idx = (f + ci) & 255;
    float cv = cs[ci][idx];
#pragma unroll
    for (int k = 0; k < 4; ++k) acc[k] = fmaf(qs[qb + k][idx], cv, acc[k]);
  }
  const float dj = dic[ci];
#pragma unroll
  for (int k = 0; k < 4; ++k) {
    float alt = dq[qb + k] + dj;
    dst[(qb + k) * 32 + ci] = fminf(-acc[k], alt);
  }
}

// ---- wave primitives for the LAP ------------------------------------------
template <int CTRL>
__device__ __forceinline__ float dpp_ror_min(float x) {
  int y = __builtin_amdgcn_update_dpp(0, __float_as_int(x), CTRL, 0xf, 0xf, true);
  return fminf(x, __int_as_float(y));
}
template <int CTRL>
__device__ __forceinline__ float dpp_ror_add(float x) {
  int y = __builtin_amdgcn_update_dpp(0, __float_as_int(x), CTRL, 0xf, 0xf, true);
  return x + __int_as_float(y);
}
__device__ __forceinline__ float rdlane_f(float x, int l) {
  return __int_as_float(__builtin_amdgcn_readlane(__float_as_int(x), l));
}
__device__ __forceinline__ float wave_min32(float x) {
  x = dpp_ror_min<0x121>(x);
  x = dpp_ror_min<0x122>(x);
  x = dpp_ror_min<0x124>(x);
  x = dpp_ror_min<0x128>(x);
  return fminf(rdlane_f(x, 0), rdlane_f(x, 16));
}

// ---- 32x32 Jonker-Volgenant: CR + parallel row reduction + greedy + SAP ---
__global__ __launch_bounds__(64) void lap_k(const float* __restrict__ sim,
                                            float* __restrict__ mcost) {
  __shared__ float Cl[1024];
  __shared__ float Cp[32][33];   // padded copy for conflict-free row reads
  __shared__ float vl[32];
  const int lane = threadIdx.x;
  const float* src = sim + (size_t)blockIdx.x * 1024;
  for (int k = lane; k < 1024; k += 64) {
    float x = src[k];
    Cl[k] = x;
    Cp[k >> 5][k & 31] = x;
  }
  if (lane >= 32) return;  // single wave: LDS ordering via waitcnt

  // ---- column reduction + greedy (lane = column) --------------------------
  float minv = LAP_INF;
  int imin = 0;
#pragma unroll
  for (int i = 0; i < 32; ++i) {
    float val = Cl[i * 32 + lane];
    if (val < minv) { minv = val; imin = i; }
  }
  float vj = minv;     // lane as column: dual v
  float u = 0.0f;      // lane as row: dual u
  int col4row = -1;    // lane as row
  int row4col = -1;    // lane as col
#pragma unroll
  for (int r = 0; r < 32; ++r) {
    unsigned long long bal = __ballot(imin == r);
    if (bal) {
      int j = 63 - __clzll(bal);
      if (lane == j) row4col = r;
      if (lane == r) col4row = j;
    }
  }
  unsigned long long freemask = __ballot(col4row < 0);

  // ---- parallel row reduction + zero-arc greedy for free rows -------------
  if (freemask) {
    vl[lane] = vj;
    __syncthreads();  // single-wave barrier: orders vl writes vs reads
    float rs = LAP_INF;  // row lane's min reduced cost (all rows in parallel)
#pragma unroll
    for (int j = 0; j < 32; ++j) rs = fminf(rs, Cp[lane][j] - vl[j]);
    if (col4row < 0) u = rs;  // feasible: all slacks of row lane >= rs
    unsigned long long fm = freemask;
    while (fm) {
      const int r = __ffsll(fm) - 1;
      fm &= fm - 1;
      float m = rdlane_f(rs, r);
      float s = Cl[r * 32 + lane] - vj;  // exact same op as inside rs-min
      unsigned long long bal = __ballot((s == m) && (row4col < 0));
      if (bal) {
        int j = __ffsll(bal) - 1;  // tight arc: s == m == u[r]
        if (lane == j) row4col = r;
        if (lane == r) col4row = j;
      }
    }
    freemask = __ballot(col4row < 0);
  }

  // ---- shortest augmenting path for remaining free rows -------------------
  while (freemask) {
    const int cur = __ffsll(freemask) - 1;
    freemask &= freemask - 1;
    float shortest = LAP_INF;
    int path = -1;
    bool SC = false;
    int i = cur;
    float minval = 0.0f;
    int sink;
    while (true) {
      float ui = rdlane_f(u, i);
      float r = minval + Cl[i * 32 + lane] - ui - vj;
      bool better = (!SC) && (r < shortest);
      shortest = better ? r : shortest;
      path = better ? i : path;
      float masked = SC ? LAP_INF : shortest;
      float mv = wave_min32(masked);
      unsigned long long bal = __ballot(masked == mv);  // exact: min keeps bits
      int j = __ffsll(bal) - 1;                         // lowest-index tie-break
      minval = mv;
      SC = SC || (lane == j);
      int rj = __builtin_amdgcn_readlane(row4col, j);
      if (rj < 0) { sink = j; break; }
      i = rj;
    }
    unsigned long long scmask = __ballot(SC);
    if (SC) vj -= minval - shortest;
    int sidx = (col4row < 0) ? lane : col4row;
    float sh_j0 = __shfl(shortest, sidx);
    bool scanned = (col4row >= 0) && ((scmask >> col4row) & 1ull) && (col4row != sink);
    if (lane == cur) u += minval;
    else if (scanned) u += minval - sh_j0;
    int j = sink;
    while (true) {
      int i2 = __builtin_amdgcn_readlane(path, j);
      int jn = __builtin_amdgcn_readlane(col4row, i2);
      if (lane == j) row4col = i2;
      if (lane == i2) col4row = j;
      j = jn;
      if (i2 == cur) break;
    }
  }
  // total assignment cost
  float cc = Cl[lane * 32 + col4row];
  cc = dpp_ror_add<0x121>(cc);
  cc = dpp_ror_add<0x122>(cc);
  cc = dpp_ror_add<0x124>(cc);
  cc = dpp_ror_add<0x128>(cc);
  float tot = rdlane_f(cc, 0) + rdlane_f(cc, 16);
  if (lane == 0) mcost[blockIdx.x] = tot;
}

// ---- head: sigmoid(sum_l mcost/S * w_l + b) -------------------------------
__global__ void final_k(const float* __restrict__ mcost,
                        const float* __restrict__ ot_w,
                        const float* __restrict__ ot_b,
                        float* __restrict__ out) {
  int b = threadIdx.x;
  if (b < 256) {
    float s = ot_b[0];
#pragma unroll
    for (int l = 0; l < 3; ++l)
      s += mcost[b * 3 + l] * (1.0f / 32.0f) * ot_w[l];
    out[b] = 1.0f / (1.0f + expf(-s));
  }
}

extern "C" void kernel_launch(void* const* d_in, const int* in_sizes, int n_in,
                              void* d_out, int out_size, void* d_ws, size_t ws_size,
                              hipStream_t stream) {
  const float* x_q  = (const float*)d_in[0];
  const float* x_c  = (const float*)d_in[1];
  const float* W0   = (const float*)d_in[2];
  const float* b0   = (const float*)d_in[3];
  const float* W1   = (const float*)d_in[4];
  const float* b1   = (const float*)d_in[5];
  const float* W2   = (const float*)d_in[6];
  const float* b2   = (const float*)d_in[7];
  const float* delp = (const float*)d_in[8];
  const float* insp = (const float*)d_in[9];
  const float* ot_w = (const float*)d_in[10];
  const float* ot_b = (const float*)d_in[11];
  const int* ei_q   = (const int*)d_in[12];
  const int* ei_c   = (const int*)d_in[13];
  float* out = (float*)d_out;

  float* ws    = (float*)d_ws;
  float* adj   = ws;                 // 512*1024              = 524288
  float* Y     = adj + 524288;       // 2*8192*256            = 4194304
  float* PAq   = Y + 4194304;        // 8192*256              = 2097152
  float* PAc   = PAq + 2097152;      // 8192*256              = 2097152
  float* sim   = PAc + 2097152;      // 768*1024              = 786432
  float* mcost = sim + 786432;       // 768
  unsigned short* WP = (unsigned short*)(mcost + 768);  // 524288 ushorts
  unsigned short* WH0 = WP;                 // 256*512
  unsigned short* WL0 = WP + 131072;
  unsigned short* WH1 = WP + 262144;        // 256*256
  unsigned short* WL1 = WP + 327680;
  unsigned short* WH2 = WP + 393216;
  unsigned short* WL2 = WP + 458752;

  const int ne = in_sizes[12] / 2;

  (void)hipMemsetAsync(adj, 0, 512 * 1024 * sizeof(float), stream);
  count_edges_k<<<dim3((ne + 255) / 256, 2), 256, 0, stream>>>(ei_q, ei_c, adj, ne);
  norm_adj_k<<<512, 256, 0, stream>>>(adj);
  wsplit_k<<<dim3(16, 8, 3), 256, 0, stream>>>(W0, W1, W2, WP);

  gemm_k<512><<<dim3(128, 2, 2), 256, 0, stream>>>(x_q, x_c, WH0, WL0, Y);
  aggsim_k<<<256, 256, 0, stream>>>(Y, adj, b0, delp, insp, sim, 0, PAq, PAc, 1);
  gemm_k<256><<<dim3(128, 2, 2), 256, 0, stream>>>(PAq, PAc, WH1, WL1, Y);
  aggsim_k<<<256, 256, 0, stream>>>(Y, adj, b1, delp + 256, insp + 256, sim, 1, PAq, PAc, 1);
  gemm_k<256><<<dim3(128, 2, 2), 256, 0, stream>>>(PAq, PAc, WH2, WL2, Y);
  aggsim_k<<<256, 256, 0, stream>>>(Y, adj, b2, delp + 512, insp + 512, sim, 2, PAq, PAc, 0);

  lap_k<<<768, 64, 0, stream>>>(sim, mcost);
  final_k<<<1, 256, 0, stream>>>(mcost, ot_w, ot_b, out);
}